// Round 12
// baseline (299.256 us; speedup 1.0000x reference)
//
#include <hip/hip_runtime.h>

// FlowNet correlation via MFMA (bf16 exact-split Gram-matrix formulation).
// out[b, dy*9+dx, y, x] = (1/256) sum_c x1[b,c,y,x] * x2[b,c,y+dy-4,x+dx-4]
// B=4 C=256 H=W=128, 9x9 displacements, zero padding.
//
// Round-16 = round-15 with the NaN bug fixed:
//  (1) halo-zero init was `if (tid < 576)` in a 512-thread block -> dy=8's
//      halo cells (tid 512..575) stayed UNINITIALIZED LDS -> NaN bf16 patterns
//      fed extracted columns (idx 132..135, wv=7). Now a strided loop covers
//      all 1152 halo cells (idx {0..3, 132..143} x 9dy x 8ci).
//  (2) X2ROW 136 -> 144: tile-1 B-frags read x' idx up to 16wv+31 = 143;
//      previously these crossed into the next dy-row / A-region (incl. more
//      uninit dwords). Now in-row and zeroed.
// Formulation (audited clean): P[x,x'] = sum_c x1[c,x] x2[c,x'] per (b,y,dy);
// out[dx,x] = P[x, x+dx-4]. mfma_f32_16x16x32_bf16, K=32 = 8ch x 4 split-slots:
// A j-seq [h,l,h,l], B j-seq [h,h,l,l] per channel -> sum = (h+l)(h+l) = exact
// product (split error ~2^-17); pairing is layout-permutation-proof (A,B share
// the same j-ordering in the same lane). D layout = HW-verified (m89)
// col=lane&15, row=(lane>>4)*4+reg. Bank-audited: A stride 10, P-read stride 34,
// x2 2-way (free). Block=(b,y): 512 thr = 8 waves = 8 x-tiles; 32 chunks.

#define MD 4
constexpr int Bc = 4, Cc = 256, Hc = 128, Wc = 128;
constexpr int HW = Hc * Wc;
constexpr int NCH = 8;                  // channels per chunk
constexpr int NKC = Cc / NCH;           // 32 chunks
constexpr int X2CS = 8;                 // ci dwords per (dy, x')
constexpr int X2NI = 144;               // x' idx 0..143 (= x2 col -4..139; >=132 zero)
constexpr int X2ROW = X2NI * X2CS;      // 1152 dw per dy row
constexpr int X2TOT = 9 * X2ROW;        // 10368 dw
constexpr int ASTR = 10;                // A row stride (dw), even, bank-clean
constexpr int ATOT = 128 * ASTR;        // 1280 dw
constexpr int SMEMDW = X2TOT + ATOT;    // 11648 dw = 46592 B
constexpr int PSTR = 33;                // P row stride (f32), conflict-free diagonals
constexpr int PWAVE = 16 * PSTR;        // 528 f32 per wave

typedef __attribute__((ext_vector_type(8))) short bf16x8;   // 8 bf16 = 4 VGPR
typedef __attribute__((ext_vector_type(4))) float f32x4;

union U8 { int i[4]; bf16x8 v; };

__device__ __forceinline__ unsigned f2bf(float v) {         // RNE f32->bf16 bits
    unsigned u = __float_as_uint(v);
    return (u + 0x7fffu + ((u >> 16) & 1u)) >> 16;
}
__device__ __forceinline__ int packsplit(float v) {         // (lo16<<16)|hi16
    unsigned hb = f2bf(v);
    float hf = __uint_as_float(hb << 16);
    unsigned lb = f2bf(v - hf);
    return (int)((lb << 16) | hb);
}
__device__ __forceinline__ bf16x8 mk_a(int e0, int e1) {    // j: [h,l,h,l | h,l,h,l]
    U8 u; u.i[0] = e0; u.i[1] = e0; u.i[2] = e1; u.i[3] = e1; return u.v;
}
__device__ __forceinline__ bf16x8 mk_b(int e0, int e1) {    // j: [h,h,l,l | h,h,l,l]
    U8 u;
    u.i[0] = (e0 << 16) | (e0 & 0xffff);
    u.i[1] = (int)(((unsigned)e0 >> 16) | ((unsigned)e0 & 0xffff0000u));
    u.i[2] = (e1 << 16) | (e1 & 0xffff);
    u.i[3] = (int)(((unsigned)e1 >> 16) | ((unsigned)e1 & 0xffff0000u));
    return u.v;
}

__global__ __launch_bounds__(512, 2)
void corr_kernel(const float* __restrict__ x1, const float* __restrict__ x2,
                 float* __restrict__ out)
{
    __shared__ int smem[SMEMDW];
    const int tid = threadIdx.x;

    // XCD grouping: consecutive-y blocks (share 8/9 x2 rows) land on one XCD.
    const int bid = blockIdx.x;
    const int t   = (bid & 7) * 64 + (bid >> 3);   // bijective on 0..511
    const int b   = t >> 7;
    const int y   = t & 127;

    const int xg   = tid & 127;        // staging x
    const int q    = tid >> 7;         // staging quarter 0..3
    const int wv   = tid >> 6;         // wave = x-tile 0..7
    const int lane = tid & 63;
    const int n    = lane & 15;        // MFMA m (A-row) / n (B-col) lane index
    const int kq   = lane >> 4;        // k-subgroup 0..3 (ci pair = 2kq, 2kq+1)

    // ---- zero ALL halo cells: idx {0..3 (left), 132..143 (right pad)} x 9dy x 8ci
    //      = 1152 cells, strided over the 512 threads (r15 bug: `if(tid<576)`
    //      left dy=8's halo uninitialized -> NaN). ----
    for (int i = tid; i < 1152; i += 512) {
        const int dy  = i >> 7;        // 0..8
        const int rem = i & 127;
        const int ii  = rem >> 3;      // 0..15
        const int ci  = rem & 7;
        const int idx = (ii < 4) ? ii : (128 + ii);   // 0..3, 132..143
        smem[dy * X2ROW + idx * X2CS + ci] = 0;
    }

    f32x4 pacc[9][2];
    #pragma unroll
    for (int d = 0; d < 9; ++d) {
        pacc[d][0] = (f32x4){0.f, 0.f, 0.f, 0.f};
        pacc[d][1] = (f32x4){0.f, 0.f, 0.f, 0.f};
    }

    const float* x2b = x2 + (size_t)b * Cc * HW;
    const float* x1b = x1 + (size_t)b * Cc * HW;

    #pragma unroll 1
    for (int k = 0; k < NKC; ++k) {
        const int c0 = k * NCH;
        __syncthreads();               // prev compute done reading smem (covers halo @k=0)
        // ---- stage x2: thread owns f = 18q..18q+17, f = dy*8+ci (pairs share dy) ----
        float va[18];
        #pragma unroll
        for (int i = 0; i < 18; ++i) {
            const int f  = 18 * q + i;
            const int dy = f >> 3;
            const int ci = f & 7;
            const int row = y + dy - MD;
            const bool rv = (unsigned)row < (unsigned)Hc;
            va[i] = rv ? x2b[((size_t)(c0 + ci) * Hc + row) * Wc + xg] : 0.f;
        }
        const float wa0 = x1b[((size_t)(c0 + 2 * q) * Hc + y) * Wc + xg];
        const float wa1 = x1b[((size_t)(c0 + 2 * q + 1) * Hc + y) * Wc + xg];
        #pragma unroll
        for (int i = 0; i < 18; i += 2) {
            const int f  = 18 * q + i;
            const int dy = f >> 3;
            const int ci = f & 7;      // even -> b64-aligned int2 store
            *(int2*)&smem[dy * X2ROW + (xg + 4) * X2CS + ci] =
                make_int2(packsplit(va[i]), packsplit(va[i + 1]));
        }
        *(int2*)&smem[X2TOT + xg * ASTR + 2 * q] =
            make_int2(packsplit(wa0), packsplit(wa1));
        __syncthreads();               // chunk k staged
        // ---- compute: A-frag once, then 9 dy x 2 x'-tiles MFMA ----
        const int2 ea = *(const int2*)&smem[X2TOT + (16 * wv + n) * ASTR + 2 * kq];
        const bf16x8 afrag = mk_a(ea.x, ea.y);
        #pragma unroll
        for (int dy = 0; dy < 9; ++dy) {
            const int base = dy * X2ROW + (16 * wv + n) * X2CS + 2 * kq;
            const int2 e0 = *(const int2*)&smem[base];                 // x' idx 16wv+n
            const int2 e1 = *(const int2*)&smem[base + 16 * X2CS];     // x' idx 16wv+16+n
            pacc[dy][0] = __builtin_amdgcn_mfma_f32_16x16x32_bf16(
                              afrag, mk_b(e0.x, e0.y), pacc[dy][0], 0, 0, 0);
            pacc[dy][1] = __builtin_amdgcn_mfma_f32_16x16x32_bf16(
                              afrag, mk_b(e1.x, e1.y), pacc[dy][1], 0, 0, 0);
        }
    }

    // ---- extraction: per dy, P -> LDS (reused), read 9 diagonals, store coalesced ----
    const float inv = 1.0f / (float)Cc;
    float* smf = (float*)smem;
    #pragma unroll
    for (int dy = 0; dy < 9; ++dy) {
        __syncthreads();               // smem free (K-loop / prev round's reads done)
        #pragma unroll
        for (int tt = 0; tt < 2; ++tt)
            #pragma unroll
            for (int r = 0; r < 4; ++r)
                smf[wv * PWAVE + (4 * kq + r) * PSTR + 16 * tt + n] = pacc[dy][tt][r];
        __syncthreads();
        #pragma unroll 1
        for (int e = tid; e < 1152; e += 512) {    // 9 dx x 128 x
            const int dx = e >> 7;
            const int x  = e & 127;
            out[(((size_t)b * 81 + dy * 9 + dx) * Hc + y) * Wc + x] =
                smf[(x >> 4) * PWAVE + (x & 15) * PSTR + (x & 15) + dx] * inv;
        }
    }
}

extern "C" void kernel_launch(void* const* d_in, const int* in_sizes, int n_in,
                              void* d_out, int out_size, void* d_ws, size_t ws_size,
                              hipStream_t stream) {
    const float* x1 = (const float*)d_in[0];
    const float* x2 = (const float*)d_in[1];
    float* out = (float*)d_out;
    corr_kernel<<<dim3(512), dim3(512), 0, stream>>>(x1, x2, out);
}